// Round 12
// baseline (515.302 us; speedup 1.0000x reference)
//
#include <hip/hip_runtime.h>
#include <hip/hip_cooperative_groups.h>
#include <stdint.h>

namespace cg = cooperative_groups;

#define N_NODES 100000
#define N_EDGES 800000
#define D 128
#define CSR_BLOCKS 512
#define CSR_THREADS 256

typedef _Float16 f16x8 __attribute__((ext_vector_type(8)));
typedef float f32x4 __attribute__((ext_vector_type(4)));

// ---------------- one-shot cooperative CSR build ----------------
// phases: zero cnt | hist+rank | local scan (98 blks) | block-sum scan | add | scatter
__global__ __launch_bounds__(CSR_THREADS) void csr_coop(const int* __restrict__ src,
                                                        const int* __restrict__ dst,
                                                        int* __restrict__ cnt,
                                                        int* __restrict__ offsets,
                                                        int* __restrict__ bs,
                                                        int* __restrict__ rank,
                                                        int* __restrict__ esrc) {
    cg::grid_group grid = cg::this_grid();
    __shared__ int sdata[CSR_THREADS];
    const int t = threadIdx.x;
    const int bid = blockIdx.x;
    const int gtid = bid * CSR_THREADS + t;
    const int gstride = CSR_BLOCKS * CSR_THREADS;  // 131072

    // P0: zero counts
    for (int i = gtid; i < N_NODES; i += gstride) cnt[i] = 0;
    grid.sync();

    // P1: histogram + per-edge rank
    for (int e = gtid; e < N_EDGES; e += gstride)
        rank[e] = atomicAdd(&cnt[dst[e]], 1);
    grid.sync();

    // P2: local exclusive scan, 1024 elems per block (first 98 blocks)
    const int nblk = (N_NODES + 1023) / 1024;  // 98
    int v[4];
    int run_keep = 0;
    if (bid < nblk) {
        const int base = bid * 1024 + t * 4;
        int s = 0;
#pragma unroll
        for (int j = 0; j < 4; ++j) {
            int i = base + j;
            v[j] = (i < N_NODES) ? cnt[i] : 0;
            s += v[j];
        }
        sdata[t] = s;
        __syncthreads();
        int incl = s;
        for (int off = 1; off < CSR_THREADS; off <<= 1) {
            int add = (t >= off) ? sdata[t - off] : 0;
            __syncthreads();
            incl += add;
            sdata[t] = incl;
            __syncthreads();
        }
        int run = incl - s;
        run_keep = run;
#pragma unroll
        for (int j = 0; j < 4; ++j) {
            int i = base + j;
            if (i < N_NODES) offsets[i] = run;
            run += v[j];
        }
        if (t == CSR_THREADS - 1) bs[bid] = incl;
    }
    grid.sync();

    // P3: scan the 98 block sums with one wave
    if (bid == 0 && t < 64) {
        int v0 = (2 * t < nblk) ? bs[2 * t] : 0;
        int v1 = (2 * t + 1 < nblk) ? bs[2 * t + 1] : 0;
        int s = v0 + v1;
        int incl = s;
        for (int off = 1; off < 64; off <<= 1) {
            int n = __shfl_up(incl, off, 64);
            if (t >= off) incl += n;
        }
        int excl = incl - s;
        if (2 * t < nblk) bs[2 * t] = excl;
        if (2 * t + 1 < nblk) bs[2 * t + 1] = excl + v0;
        if (t == 63) offsets[N_NODES] = incl;  // == N_EDGES
    }
    grid.sync();

    // P4: add block prefix
    if (bid < nblk) {
        const int base = bid * 1024 + t * 4;
        const int add = bs[bid];
#pragma unroll
        for (int j = 0; j < 4; ++j) {
            int i = base + j;
            if (i < N_NODES) offsets[i] += add;
        }
    }
    grid.sync();

    // P5: scatter edge sources into CSR order
    for (int e = gtid; e < N_EDGES; e += gstride)
        esrc[offsets[dst[e]] + rank[e]] = src[e];
}

// ---------------- register-B MFMA GEMM, double-buffered strips ----------------
// blockIdx.x&1==0: pre = x@Ws + b -> out (fp32);  ==1: y2 = x@Wn -> ws (f16)
__global__ __launch_bounds__(256) void gemm_reg(const float* __restrict__ x,
                                                const float* __restrict__ Ws,
                                                const float* __restrict__ Wn,
                                                const float* __restrict__ bias,
                                                float* __restrict__ pre,
                                                _Float16* __restrict__ y2) {
    const int half = blockIdx.x & 1;
    const int bid = blockIdx.x >> 1;
    const int nb = gridDim.x >> 1;
    const int tid = threadIdx.x;
    const int w = tid >> 6;
    const int lane = tid & 63;
    const int lr = lane & 15;
    const int lk = (lane >> 4) * 8;
    const int wc = w & 1;
    const int ws_ = w >> 1;

    const float* __restrict__ W = half ? Wn : Ws;

    // B fragments: bfrag[ks][fc] covers k = ks*32+lk..+7, col = wc*64+fc*16+lr
    f16x8 bfrag[4][4];
#pragma unroll
    for (int ks = 0; ks < 4; ++ks) {
#pragma unroll
        for (int fc = 0; fc < 4; ++fc) {
            const int col = wc * 64 + fc * 16 + lr;
            const int kb = ks * 32 + lk;
            f16x8 h;
#pragma unroll
            for (int j = 0; j < 8; ++j) h[j] = (_Float16)W[(long)(kb + j) * D + col];
            bfrag[ks][fc] = h;
        }
    }
    float bv[4];
    if (half == 0) {
#pragma unroll
        for (int fc = 0; fc < 4; ++fc) bv[fc] = bias[wc * 64 + fc * 16 + lr];
    }

    auto loadA = [&](f32x4* A, int s) {
        const float* __restrict__ xr = &x[(long)(s * 16 + lr) * D];
#pragma unroll
        for (int ks = 0; ks < 4; ++ks) {
            A[2 * ks] = *(const f32x4*)&xr[ks * 32 + lk];
            A[2 * ks + 1] = *(const f32x4*)&xr[ks * 32 + lk + 4];
        }
    };
    auto compStore = [&](const f32x4* A, int s) {
        f32x4 acc[4];
#pragma unroll
        for (int fc = 0; fc < 4; ++fc) acc[fc] = (f32x4){0.f, 0.f, 0.f, 0.f};
#pragma unroll
        for (int ks = 0; ks < 4; ++ks) {
            f16x8 af;
#pragma unroll
            for (int j = 0; j < 4; ++j) {
                af[j] = (_Float16)A[2 * ks][j];
                af[4 + j] = (_Float16)A[2 * ks + 1][j];
            }
#pragma unroll
            for (int fc = 0; fc < 4; ++fc)
                acc[fc] = __builtin_amdgcn_mfma_f32_16x16x32_f16(af, bfrag[ks][fc],
                                                                 acc[fc], 0, 0, 0);
        }
        const int rb = s * 16 + (lane >> 4) * 4;
        if (half == 0) {
#pragma unroll
            for (int fc = 0; fc < 4; ++fc) {
                const int col = wc * 64 + fc * 16 + lr;
#pragma unroll
                for (int i = 0; i < 4; ++i)
                    pre[(long)(rb + i) * D + col] = acc[fc][i] + bv[fc];
            }
        } else {
#pragma unroll
            for (int fc = 0; fc < 4; ++fc) {
                const int col = wc * 64 + fc * 16 + lr;
#pragma unroll
                for (int i = 0; i < 4; ++i)
                    y2[(long)(rb + i) * D + col] = (_Float16)acc[fc][i];
            }
        }
    };

    const int nstrip = N_NODES / 16;  // 6250, exact
    const int stride = nb * 2;
    int s = bid * 2 + ws_;
    int snext = s + stride;

    f32x4 A0[8], A1[8];
    loadA(A0, s);
    while (true) {
        bool hn = snext < nstrip;
        if (hn) loadA(A1, snext);
        compStore(A0, s);
        if (!hn) break;
        s = snext;
        snext += stride;
        hn = snext < nstrip;
        if (hn) loadA(A0, snext);
        compStore(A1, s);
        if (!hn) break;
        s = snext;
        snext += stride;
    }
}

// ---------------- wave-per-node aggregate + epilogue (no LDS) ----------------
// out[n] = relu(pre[n] + mean_{e: dst=n} y2[src[e]])   (in-place, pre==out)
__global__ __launch_bounds__(256) void agg_wave(const _Float16* __restrict__ y2,
                                                const int* __restrict__ offsets,
                                                const int* __restrict__ esrc,
                                                float* __restrict__ out) {
    const int n = blockIdx.x * 4 + (threadIdx.x >> 6);  // node (grid exact)
    const int lane = threadIdx.x & 63;
    const int slot = lane >> 4;   // 0..3
    const int c8 = lane & 15;     // halfs c8*8..+7
    const int s = offsets[n];
    const int e = offsets[n + 1];
    float a[8] = {0.f, 0.f, 0.f, 0.f, 0.f, 0.f, 0.f, 0.f};
    for (int j = s + slot; j < e; j += 4) {
        int sn = esrc[j];
        f16x8 v = *(const f16x8*)&y2[(long)sn * D + c8 * 8];
#pragma unroll
        for (int i = 0; i < 8; ++i) a[i] += (float)v[i];
    }
#pragma unroll
    for (int i = 0; i < 8; ++i) {
        a[i] += __shfl_xor(a[i], 16, 64);
        a[i] += __shfl_xor(a[i], 32, 64);
    }
    if (slot == 0) {
        const int deg = e - s;
        const float inv = (deg > 0) ? 1.f / (float)deg : 0.f;
        float4 p0 = *(const float4*)&out[(long)n * D + c8 * 8];
        float4 p1 = *(const float4*)&out[(long)n * D + c8 * 8 + 4];
        float4 o0, o1;
        o0.x = fmaxf(p0.x + a[0] * inv, 0.f);
        o0.y = fmaxf(p0.y + a[1] * inv, 0.f);
        o0.z = fmaxf(p0.z + a[2] * inv, 0.f);
        o0.w = fmaxf(p0.w + a[3] * inv, 0.f);
        o1.x = fmaxf(p1.x + a[4] * inv, 0.f);
        o1.y = fmaxf(p1.y + a[5] * inv, 0.f);
        o1.z = fmaxf(p1.z + a[6] * inv, 0.f);
        o1.w = fmaxf(p1.w + a[7] * inv, 0.f);
        *(float4*)&out[(long)n * D + c8 * 8] = o0;
        *(float4*)&out[(long)n * D + c8 * 8 + 4] = o1;
    }
}

// ---------------- launch ----------------

extern "C" void kernel_launch(void* const* d_in, const int* in_sizes, int n_in,
                              void* d_out, int out_size, void* d_ws, size_t ws_size,
                              hipStream_t stream) {
    const float* x  = (const float*)d_in[0];
    const int* src  = (const int*)d_in[1];
    const int* dst  = (const int*)d_in[2];
    const float* Ws = (const float*)d_in[3];
    const float* Wn = (const float*)d_in[4];
    const float* b  = (const float*)d_in[5];
    float* out = (float*)d_out;

    int* cnt     = (int*)d_ws;                 // N
    int* offsets = cnt + N_NODES;              // N+1
    int* bs      = offsets + N_NODES + 1;      // 128
    int* rank    = bs + 128;                   // E
    int* esrc    = rank + N_EDGES;             // E
    uintptr_t p = (uintptr_t)(esrc + N_EDGES);
    p = (p + 255) & ~(uintptr_t)255;
    _Float16* y2 = (_Float16*)p;               // N*D f16

    void* csr_args[] = {(void*)&src, (void*)&dst, (void*)&cnt, (void*)&offsets,
                        (void*)&bs, (void*)&rank, (void*)&esrc};
    hipLaunchCooperativeKernel((void*)csr_coop, dim3(CSR_BLOCKS), dim3(CSR_THREADS),
                               csr_args, 0, stream);
    gemm_reg<<<1280, 256, 0, stream>>>(x, Ws, Wn, b, out, y2);
    agg_wave<<<N_NODES / 4, 256, 0, stream>>>(y2, offsets, esrc, out);
}

// Round 13
// 246.069 us; speedup vs baseline: 2.0941x; 2.0941x over previous
//
#include <hip/hip_runtime.h>
#include <stdint.h>

#define N_NODES 100000
#define N_EDGES 800000
#define D 128

typedef _Float16 f16x8 __attribute__((ext_vector_type(8)));
typedef float f32x4 __attribute__((ext_vector_type(4)));

// ---------------- CSR build ----------------

// 4 edges per thread; rank[e] = position of edge e within its dst bucket
__global__ void hist_rank4(const int* __restrict__ dst, int* __restrict__ cnt,
                           int* __restrict__ rank) {
    int e4 = blockIdx.x * blockDim.x + threadIdx.x;
    if (e4 < N_EDGES / 4) {
        int4 d = ((const int4*)dst)[e4];
        int4 r;
        r.x = atomicAdd(&cnt[d.x], 1);
        r.y = atomicAdd(&cnt[d.y], 1);
        r.z = atomicAdd(&cnt[d.z], 1);
        r.w = atomicAdd(&cnt[d.w], 1);
        ((int4*)rank)[e4] = r;
    }
}

// local exclusive scan of 1024 counts per block -> raw offsets + block sums
__global__ void scan_local(const int* __restrict__ cnt, int* __restrict__ offsets,
                           int* __restrict__ bs) {
    __shared__ int sdata[256];
    const int t = threadIdx.x;
    const int base = blockIdx.x * 1024 + t * 4;
    int v[4];
    int s = 0;
#pragma unroll
    for (int j = 0; j < 4; ++j) {
        int i = base + j;
        v[j] = (i < N_NODES) ? cnt[i] : 0;
        s += v[j];
    }
    sdata[t] = s;
    __syncthreads();
    int incl = s;
    for (int off = 1; off < 256; off <<= 1) {
        int add = (t >= off) ? sdata[t - off] : 0;
        __syncthreads();
        incl += add;
        sdata[t] = incl;
        __syncthreads();
    }
    int run = incl - s;
#pragma unroll
    for (int j = 0; j < 4; ++j) {
        int i = base + j;
        if (i < N_NODES) offsets[i] = run;
        run += v[j];
    }
    if (t == 255) bs[blockIdx.x] = incl;
}

// one wave scans the (<=128) block sums (in place)
__global__ void scan_block2(int* __restrict__ bs, int nblk) {
    int t = threadIdx.x;  // 0..63
    int v0 = (2 * t < nblk) ? bs[2 * t] : 0;
    int v1 = (2 * t + 1 < nblk) ? bs[2 * t + 1] : 0;
    int s = v0 + v1;
    int incl = s;
    for (int off = 1; off < 64; off <<= 1) {
        int n = __shfl_up(incl, off, 64);
        if (t >= off) incl += n;
    }
    int excl = incl - s;
    if (2 * t < nblk) bs[2 * t] = excl;
    if (2 * t + 1 < nblk) bs[2 * t + 1] = excl + v0;
}

// scatter with on-the-fly final offset: esrc[off_raw[d] + bs[d>>10] + rank] = src
__global__ void scatter_f(const int* __restrict__ src, const int* __restrict__ dst,
                          const int* __restrict__ offsets, const int* __restrict__ bs,
                          const int* __restrict__ rank, int* __restrict__ esrc) {
    int e4 = blockIdx.x * blockDim.x + threadIdx.x;
    if (e4 < N_EDGES / 4) {
        int4 d = ((const int4*)dst)[e4];
        int4 sr = ((const int4*)src)[e4];
        int4 r = ((const int4*)rank)[e4];
        esrc[offsets[d.x] + bs[d.x >> 10] + r.x] = sr.x;
        esrc[offsets[d.y] + bs[d.y >> 10] + r.y] = sr.y;
        esrc[offsets[d.z] + bs[d.z >> 10] + r.z] = sr.z;
        esrc[offsets[d.w] + bs[d.w >> 10] + r.w] = sr.w;
    }
}

// ---------------- register-B MFMA GEMM, double-buffered strips ----------------
// blockIdx.x&1==0: pre = x@Ws + b -> out (fp32);  ==1: y2 = x@Wn -> ws (f16)
__global__ __launch_bounds__(256) void gemm_reg(const float* __restrict__ x,
                                                const float* __restrict__ Ws,
                                                const float* __restrict__ Wn,
                                                const float* __restrict__ bias,
                                                float* __restrict__ pre,
                                                _Float16* __restrict__ y2) {
    const int half = blockIdx.x & 1;
    const int bid = blockIdx.x >> 1;
    const int nb = gridDim.x >> 1;
    const int tid = threadIdx.x;
    const int w = tid >> 6;
    const int lane = tid & 63;
    const int lr = lane & 15;
    const int lk = (lane >> 4) * 8;
    const int wc = w & 1;
    const int ws_ = w >> 1;

    const float* __restrict__ W = half ? Wn : Ws;

    f16x8 bfrag[4][4];
#pragma unroll
    for (int ks = 0; ks < 4; ++ks) {
#pragma unroll
        for (int fc = 0; fc < 4; ++fc) {
            const int col = wc * 64 + fc * 16 + lr;
            const int kb = ks * 32 + lk;
            f16x8 h;
#pragma unroll
            for (int j = 0; j < 8; ++j) h[j] = (_Float16)W[(long)(kb + j) * D + col];
            bfrag[ks][fc] = h;
        }
    }
    float bv[4];
    if (half == 0) {
#pragma unroll
        for (int fc = 0; fc < 4; ++fc) bv[fc] = bias[wc * 64 + fc * 16 + lr];
    }

    auto loadA = [&](f32x4* A, int s) {
        const float* __restrict__ xr = &x[(long)(s * 16 + lr) * D];
#pragma unroll
        for (int ks = 0; ks < 4; ++ks) {
            A[2 * ks] = *(const f32x4*)&xr[ks * 32 + lk];
            A[2 * ks + 1] = *(const f32x4*)&xr[ks * 32 + lk + 4];
        }
    };
    auto compStore = [&](const f32x4* A, int s) {
        f32x4 acc[4];
#pragma unroll
        for (int fc = 0; fc < 4; ++fc) acc[fc] = (f32x4){0.f, 0.f, 0.f, 0.f};
#pragma unroll
        for (int ks = 0; ks < 4; ++ks) {
            f16x8 af;
#pragma unroll
            for (int j = 0; j < 4; ++j) {
                af[j] = (_Float16)A[2 * ks][j];
                af[4 + j] = (_Float16)A[2 * ks + 1][j];
            }
#pragma unroll
            for (int fc = 0; fc < 4; ++fc)
                acc[fc] = __builtin_amdgcn_mfma_f32_16x16x32_f16(af, bfrag[ks][fc],
                                                                 acc[fc], 0, 0, 0);
        }
        const int rb = s * 16 + (lane >> 4) * 4;
        if (half == 0) {
#pragma unroll
            for (int fc = 0; fc < 4; ++fc) {
                const int col = wc * 64 + fc * 16 + lr;
#pragma unroll
                for (int i = 0; i < 4; ++i)
                    pre[(long)(rb + i) * D + col] = acc[fc][i] + bv[fc];
            }
        } else {
#pragma unroll
            for (int fc = 0; fc < 4; ++fc) {
                const int col = wc * 64 + fc * 16 + lr;
#pragma unroll
                for (int i = 0; i < 4; ++i)
                    y2[(long)(rb + i) * D + col] = (_Float16)acc[fc][i];
            }
        }
    };

    const int nstrip = N_NODES / 16;  // 6250, exact
    const int stride = nb * 2;
    int s = bid * 2 + ws_;
    int snext = s + stride;

    f32x4 A0[8], A1[8];
    loadA(A0, s);
    while (true) {
        bool hn = snext < nstrip;
        if (hn) loadA(A1, snext);
        compStore(A0, s);
        if (!hn) break;
        s = snext;
        snext += stride;
        hn = snext < nstrip;
        if (hn) loadA(A0, snext);
        compStore(A1, s);
        if (!hn) break;
        s = snext;
        snext += stride;
    }
}

// ---------------- wave-per-node aggregate + epilogue (no LDS) ----------------
// out[n] = relu(pre[n] + mean_{e: dst=n} y2[src[e]])   (in-place, pre==out)
// offsets are RAW local scans; final = offsets[n] + bs[n>>10].
__global__ __launch_bounds__(256) void agg_wave2(const _Float16* __restrict__ y2,
                                                 const int* __restrict__ offsets,
                                                 const int* __restrict__ bs,
                                                 const int* __restrict__ esrc,
                                                 float* __restrict__ out) {
    const int n = blockIdx.x * 4 + (threadIdx.x >> 6);  // node (grid exact)
    const int lane = threadIdx.x & 63;
    const int slot = lane >> 4;   // 0..3
    const int c8 = lane & 15;     // halfs c8*8..+7
    const int s = offsets[n] + bs[n >> 10];
    const int e = (n == N_NODES - 1) ? N_EDGES : offsets[n + 1] + bs[(n + 1) >> 10];
    float a[8] = {0.f, 0.f, 0.f, 0.f, 0.f, 0.f, 0.f, 0.f};
    for (int j = s + slot; j < e; j += 4) {
        int sn = esrc[j];
        f16x8 v = *(const f16x8*)&y2[(long)sn * D + c8 * 8];
#pragma unroll
        for (int i = 0; i < 8; ++i) a[i] += (float)v[i];
    }
#pragma unroll
    for (int i = 0; i < 8; ++i) {
        a[i] += __shfl_xor(a[i], 16, 64);
        a[i] += __shfl_xor(a[i], 32, 64);
    }
    if (slot == 0) {
        const int deg = e - s;
        const float inv = (deg > 0) ? 1.f / (float)deg : 0.f;
        float4 p0 = *(const float4*)&out[(long)n * D + c8 * 8];
        float4 p1 = *(const float4*)&out[(long)n * D + c8 * 8 + 4];
        float4 o0, o1;
        o0.x = fmaxf(p0.x + a[0] * inv, 0.f);
        o0.y = fmaxf(p0.y + a[1] * inv, 0.f);
        o0.z = fmaxf(p0.z + a[2] * inv, 0.f);
        o0.w = fmaxf(p0.w + a[3] * inv, 0.f);
        o1.x = fmaxf(p1.x + a[4] * inv, 0.f);
        o1.y = fmaxf(p1.y + a[5] * inv, 0.f);
        o1.z = fmaxf(p1.z + a[6] * inv, 0.f);
        o1.w = fmaxf(p1.w + a[7] * inv, 0.f);
        *(float4*)&out[(long)n * D + c8 * 8] = o0;
        *(float4*)&out[(long)n * D + c8 * 8 + 4] = o1;
    }
}

// ---------------- launch ----------------

extern "C" void kernel_launch(void* const* d_in, const int* in_sizes, int n_in,
                              void* d_out, int out_size, void* d_ws, size_t ws_size,
                              hipStream_t stream) {
    const float* x  = (const float*)d_in[0];
    const int* src  = (const int*)d_in[1];
    const int* dst  = (const int*)d_in[2];
    const float* Ws = (const float*)d_in[3];
    const float* Wn = (const float*)d_in[4];
    const float* b  = (const float*)d_in[5];
    float* out = (float*)d_out;

    int* cnt     = (int*)d_ws;                 // N
    int* offsets = cnt + N_NODES;              // N+1
    int* bs      = offsets + N_NODES + 1;      // 128
    int* rank    = bs + 128;                   // E
    int* esrc    = rank + N_EDGES;             // E
    uintptr_t p = (uintptr_t)(esrc + N_EDGES);
    p = (p + 255) & ~(uintptr_t)255;
    _Float16* y2 = (_Float16*)p;               // N*D f16

    const int nblk_scan = (N_NODES + 1023) / 1024;  // 98

    hipMemsetAsync(cnt, 0, N_NODES * sizeof(int), stream);
    hist_rank4<<<(N_EDGES / 4 + 255) / 256, 256, 0, stream>>>(dst, cnt, rank);
    scan_local<<<nblk_scan, 256, 0, stream>>>(cnt, offsets, bs);
    scan_block2<<<1, 64, 0, stream>>>(bs, nblk_scan);
    scatter_f<<<(N_EDGES / 4 + 255) / 256, 256, 0, stream>>>(src, dst, offsets, bs,
                                                             rank, esrc);
    gemm_reg<<<1280, 256, 0, stream>>>(x, Ws, Wn, b, out, y2);
    agg_wave2<<<N_NODES / 4, 256, 0, stream>>>(y2, offsets, bs, esrc, out);
}